// Round 5
// baseline (4189.371 us; speedup 1.0000x reference)
//
#include <hip/hip_runtime.h>
#include <cstdio>
#include <cstdint>

typedef _Float16 f16;
typedef __attribute__((ext_vector_type(8))) _Float16 f16x8;
typedef __attribute__((ext_vector_type(4))) float f32x4;
typedef unsigned int u32;
typedef unsigned long long u64;

static constexpr int NB = 8192;
static constexpr int NC = 4;
static constexpr int NK = 8192;
static constexpr int ND = 1024;
static constexpr int BM = 128, BN = 128, BK = 32;
static constexpr int MT = NB / BM;   // 64
static constexpr int NT = NK / BN;   // 64
static constexpr int KT = ND / BK;   // 32
static constexpr float SCALE_X = 1024.f;   // 2^10
static constexpr float SCALE_E = 4096.f;   // 2^12
static constexpr float RESCUE_THR = 1.4e-4f;   // score-gap; = 2.8e-4 dist-gap

static constexpr long XQ_OFF = (long)NB * NC * ND;   // 33554432

__device__ __forceinline__ void glds16(const void* g, void* l) {
  __builtin_amdgcn_global_load_lds((const __attribute__((address_space(1))) u32*)g,
                                   (__attribute__((address_space(3))) u32*)l, 16, 0, 0);
}

__device__ __forceinline__ bool lt2(float s, int i, float so, int io) {
  return s < so || (s == so && i < io);
}
__device__ __forceinline__ void merge_top2(float& s1, int& i1, float& s2, int& i2,
                                           float o1, int oi1, float o2, int oi2) {
  float a1, b1; int ai1, bi1;
  if (lt2(o1, oi1, s1, i1)) { a1 = o1; ai1 = oi1; b1 = s1; bi1 = i1; }
  else                      { a1 = s1; ai1 = i1;  b1 = o1; bi1 = oi1; }
  float c2 = s2; int ci2 = i2;
  if (lt2(o2, oi2, c2, ci2)) { c2 = o2; ci2 = oi2; }
  if (lt2(b1, bi1, c2, ci2)) { c2 = b1; ci2 = bi1; }
  s1 = a1; i1 = ai1; s2 = c2; i2 = ci2;
}
__device__ __forceinline__ bool lt2d(double s, int i, double so, int io) {
  return s < so || (s == so && i < io);
}
__device__ __forceinline__ void merge_top2d(double& s1, int& i1, double& s2, int& i2,
                                            double o1, int oi1, double o2, int oi2) {
  double a1, b1; int ai1, bi1;
  if (lt2d(o1, oi1, s1, i1)) { a1 = o1; ai1 = oi1; b1 = s1; bi1 = i1; }
  else                       { a1 = s1; ai1 = i1;  b1 = o1; bi1 = oi1; }
  double c2 = s2; int ci2 = i2;
  if (lt2d(o2, oi2, c2, ci2)) { c2 = o2; ci2 = oi2; }
  if (lt2d(b1, bi1, c2, ci2)) { c2 = b1; ci2 = bi1; }
  s1 = a1; i1 = ai1; s2 = c2; i2 = ci2;
}

// ---------------- prep: fp32 -> (hi,lo) fp16 split, GEMM-tiled layout ----------------
__global__ __launch_bounds__(256) void prep_split(const float* __restrict__ src,
                                                  f16* __restrict__ hi, f16* __restrict__ lo,
                                                  int is_x) {
  int bid = blockIdx.x;
  int kt = bid & (KT - 1);
  int tile = (bid >> 5) & 63;
  int c = bid >> 11;
  int t = threadIdx.x;
  int row = t >> 1, h = t & 1;
  long srow = is_x ? ((long)(tile * BM + row) * NC + c)
                   : ((long)c * NK + tile * BN + row);
  const float* s = src + srow * ND + kt * BK + h * 16;
  float sc = is_x ? SCALE_X : SCALE_E;
  float vbuf[16];
#pragma unroll
  for (int j = 0; j < 4; ++j) {
    float4 v = *(const float4*)(s + j * 4);
    vbuf[j*4+0]=v.x; vbuf[j*4+1]=v.y; vbuf[j*4+2]=v.z; vbuf[j*4+3]=v.w;
  }
  f16 hv[16], lv[16];
#pragma unroll
  for (int j = 0; j < 16; ++j) {
    float v = vbuf[j] * sc;
    f16 hh = (f16)v;
    hv[j] = hh;
    lv[j] = (f16)(v - (float)hh);
  }
  long tb = (long)bid * (BM * BK);
#pragma unroll
  for (int kb = 0; kb < 2; ++kb) {
    long off = tb + (((long)(h*2 + kb) * BM + row) << 3);
    f16x8 hx, lx;
#pragma unroll
    for (int e = 0; e < 8; ++e) { hx[e] = hv[kb*8+e]; lx[e] = lv[kb*8+e]; }
    *(f16x8*)(hi + off) = hx;
    *(f16x8*)(lo + off) = lx;
  }
}

// ---------------- e2 (fp32, any build — only used inside the monotone score) --------
__global__ __launch_bounds__(256) void row2_np(const float* __restrict__ src,
                                               float* __restrict__ dst) {
  int row = blockIdx.x * 32 + (threadIdx.x >> 3);
  int blk = threadIdx.x & 7;
  const float* p = src + (long)row * ND + blk * 128;
  float r[8];
  float4 a0 = *(const float4*)(p);
  float4 a1 = *(const float4*)(p + 4);
  r[0] = a0.x*a0.x; r[1] = a0.y*a0.y; r[2] = a0.z*a0.z; r[3] = a0.w*a0.w;
  r[4] = a1.x*a1.x; r[5] = a1.y*a1.y; r[6] = a1.z*a1.z; r[7] = a1.w*a1.w;
#pragma unroll
  for (int i = 1; i < 16; ++i) {
    float4 b0 = *(const float4*)(p + i * 8);
    float4 b1 = *(const float4*)(p + i * 8 + 4);
    r[0] += b0.x*b0.x; r[1] += b0.y*b0.y; r[2] += b0.z*b0.z; r[3] += b0.w*b0.w;
    r[4] += b1.x*b1.x; r[5] += b1.y*b1.y; r[6] += b1.z*b1.z; r[7] += b1.w*b1.w;
  }
  float res = ((r[0]+r[1])+(r[2]+r[3])) + ((r[4]+r[5])+(r[6]+r[7]));
  res += __shfl_xor(res, 1);
  res += __shfl_xor(res, 2);
  res += __shfl_xor(res, 4);
  if (blk == 0) dst[row] = res;
}

// ---------------- fused split-GEMM + running top-2 of score = 0.5*e2 - xe ----------
__global__ __launch_bounds__(256, 2) void vq_gemm(
    const f16* __restrict__ xh, const f16* __restrict__ xl,
    const f16* __restrict__ cbh, const f16* __restrict__ cbl,
    const float* __restrict__ e2np,
    u64* __restrict__ wsA, u64* __restrict__ wsB) {
  __shared__ char smem[65536];
  int bid = blockIdx.x;
  int nh = bid & 1;
  int mt = (bid >> 1) & (MT - 1);
  int c  = bid >> 7;
  int tid = threadIdx.x;
  int lane = tid & 63;
  int wid = tid >> 6;
  int g = lane >> 4, r16 = lane & 15;
  int wm = wid >> 1, wn = wid & 1;
  int m0 = wm * 64, n0 = wn * 64;
  int nt0 = nh * (NT / 2);

  const f16* aH = xh + ((long)(c * MT + mt) * KT) * (BM * BK);
  const f16* aL = xl + ((long)(c * MT + mt) * KT) * (BM * BK);

  f32x4 acc[4][4];
#pragma unroll
  for (int i = 0; i < 4; ++i)
#pragma unroll
    for (int j = 0; j < 4; ++j) acc[i][j] = f32x4{0.f, 0.f, 0.f, 0.f};

  float run_s[4][4], run_s2[4][4];
  int run_i[4][4], run_i2[4][4];
#pragma unroll
  for (int i = 0; i < 4; ++i)
#pragma unroll
    for (int j = 0; j < 4; ++j) {
      run_s[i][j] = 1e30f; run_s2[i][j] = 1e30f;
      run_i[i][j] = 0x7fffffff; run_i2[i][j] = 0x7fffffff;
    }

  int wb  = (tid & 192) << 4;
  int t16 = tid << 4;

  auto stage = [&](int t) {
    int ntl = t >> 5;
    int kt  = t & 31;
    int nt  = nt0 + ntl;
    char* sb = smem + ((t & 1) << 15);
    const char* gah = (const char*)(aH + (long)kt * (BM * BK)) + t16;
    const char* gal = (const char*)(aL + (long)kt * (BM * BK)) + t16;
    const char* gbh = (const char*)(cbh + ((long)(c * NT + nt) * KT + kt) * (BN * BK)) + t16;
    const char* gbl = (const char*)(cbl + ((long)(c * NT + nt) * KT + kt) * (BN * BK)) + t16;
    char* l0 = sb + wb;
    glds16(gah,        l0);
    glds16(gah + 4096, l0 + 4096);
    glds16(gal,        l0 + 8192);
    glds16(gal + 4096, l0 + 12288);
    glds16(gbh,        l0 + 16384);
    glds16(gbh + 4096, l0 + 20480);
    glds16(gbl,        l0 + 24576);
    glds16(gbl + 4096, l0 + 28672);
  };

  stage(0);
  const int TSTEPS = (NT / 2) * KT;   // 1024
  for (int t = 0; t < TSTEPS; ++t) {
    __syncthreads();
    if (t + 1 < TSTEPS) stage(t + 1);
    const char* base = smem + ((t & 1) << 15);
    f16x8 fa_h[4], fa_l[4], fb_h[4], fb_l[4];
#pragma unroll
    for (int mf = 0; mf < 4; ++mf) {
      int off = (g * BM + m0 + mf * 16 + r16) << 4;
      fa_h[mf] = *(const f16x8*)(base + off);
      fa_l[mf] = *(const f16x8*)(base + 8192 + off);
    }
#pragma unroll
    for (int nf = 0; nf < 4; ++nf) {
      int off = (g * BN + n0 + nf * 16 + r16) << 4;
      fb_h[nf] = *(const f16x8*)(base + 16384 + off);
      fb_l[nf] = *(const f16x8*)(base + 24576 + off);
    }
#pragma unroll
    for (int mf = 0; mf < 4; ++mf)
#pragma unroll
      for (int nf = 0; nf < 4; ++nf) {
        acc[mf][nf] = __builtin_amdgcn_mfma_f32_16x16x32_f16(fa_h[mf], fb_h[nf], acc[mf][nf], 0, 0, 0);
        acc[mf][nf] = __builtin_amdgcn_mfma_f32_16x16x32_f16(fa_h[mf], fb_l[nf], acc[mf][nf], 0, 0, 0);
        acc[mf][nf] = __builtin_amdgcn_mfma_f32_16x16x32_f16(fa_l[mf], fb_h[nf], acc[mf][nf], 0, 0, 0);
      }

    if ((t & 31) == 31) {
      int nt = nt0 + (t >> 5);
      float he2[4]; int col[4];
#pragma unroll
      for (int nf = 0; nf < 4; ++nf) {
        col[nf] = nt * BN + n0 + nf * 16 + r16;
        he2[nf] = 0.5f * e2np[c * NK + col[nf]];
      }
#pragma unroll
      for (int mf = 0; mf < 4; ++mf)
#pragma unroll
        for (int q = 0; q < 4; ++q) {
          // score = 0.5*e2 - xe  (monotone in true dist per row)
          float s1 = __fmaf_rn(acc[mf][0][q], -0x1p-22f, he2[0]);
          int i1 = col[0];
          float s2 = 1e30f; int i2 = 0x7fffffff;
#pragma unroll
          for (int nf = 1; nf < 4; ++nf) {
            float sv = __fmaf_rn(acc[mf][nf][q], -0x1p-22f, he2[nf]);
            int ci = col[nf];
            if (lt2(sv, ci, s1, i1)) { s2 = s1; i2 = i1; s1 = sv; i1 = ci; }
            else if (lt2(sv, ci, s2, i2)) { s2 = sv; i2 = ci; }
          }
#pragma unroll
          for (int w = 1; w < 16; w <<= 1) {
            float o1 = __shfl_xor(s1, w);
            int  oi1 = __shfl_xor(i1, w);
            float o2 = __shfl_xor(s2, w);
            int  oi2 = __shfl_xor(i2, w);
            merge_top2(s1, i1, s2, i2, o1, oi1, o2, oi2);
          }
          merge_top2(run_s[mf][q], run_i[mf][q], run_s2[mf][q], run_i2[mf][q],
                     s1, i1, s2, i2);
        }
#pragma unroll
      for (int mf = 0; mf < 4; ++mf)
#pragma unroll
        for (int nf = 0; nf < 4; ++nf)
          acc[mf][nf] = f32x4{0.f, 0.f, 0.f, 0.f};
    }
  }

  if (r16 == 0) {
    int slot = nh * 2 + wn;
#pragma unroll
    for (int mf = 0; mf < 4; ++mf)
#pragma unroll
      for (int q = 0; q < 4; ++q) {
        int brow = mt * BM + m0 + mf * 16 + g * 4 + q;
        long idx = ((long)brow * NC + c) * 4 + slot;
        wsA[idx] = ((u64)__float_as_uint(run_s[mf][q])  << 32) | (u32)run_i[mf][q];
        wsB[idx] = ((u64)__float_as_uint(run_s2[mf][q]) << 32) | (u32)run_i2[mf][q];
      }
  }
}

// ---------------- rescue: fp64 truth top-2 + np-quantization tie verdict ----------
__global__ __launch_bounds__(256) void rescue_kernel(
    const float* __restrict__ x, const float* __restrict__ cb,
    const u64* __restrict__ wsA, const u64* __restrict__ wsB,
    int* __restrict__ fidx) {
  int row = blockIdx.x;                // b*NC + c
  __shared__ int s_flag, s_idx;
  __shared__ float xs[ND];
  __shared__ double rb1[4], rb2[4];
  __shared__ int rk1[4], rk2[4];
  __shared__ int sAB[2];
  __shared__ double sh_xe[2], sh_e2[2], sh_x2;
  int t = threadIdx.x;
  if (t == 0) {
    float g1 = 1e30f, g2 = 1e30f; int gi1 = 0x7fffffff, gi2 = 0x7fffffff;
    for (int s = 0; s < 4; ++s) {
      u64 a = wsA[(long)row * 4 + s];
      u64 b = wsB[(long)row * 4 + s];
      merge_top2(g1, gi1, g2, gi2,
                 __uint_as_float((u32)(a >> 32)), (int)(u32)(a & 0xffffffffu),
                 __uint_as_float((u32)(b >> 32)), (int)(u32)(b & 0xffffffffu));
    }
    s_idx = gi1;
    s_flag = (__fsub_rn(g2, g1) < RESCUE_THR) ? 1 : 0;
  }
  __syncthreads();
  if (!s_flag) {
    if (t == 0) fidx[row] = s_idx;
    return;
  }
  int c = row & (NC - 1);
  const float* xr = x + (long)row * ND;
  for (int i = t; i < ND; i += 256) xs[i] = xr[i];
  __syncthreads();
  // full fp64 rescan, per-thread top-2
  double b1 = 1e300, b2 = 1e300; int k1 = 0x7fffffff, k2 = 0x7fffffff;
  for (int k = t; k < NK; k += 256) {
    const float* e = cb + ((long)c * NK + k) * ND;
    double d0 = 0, d1 = 0, d2 = 0, d3 = 0;
    for (int j = 0; j < ND; j += 4) {
      double f0 = (double)xs[j]     - (double)e[j];
      double f1 = (double)xs[j + 1] - (double)e[j + 1];
      double f2 = (double)xs[j + 2] - (double)e[j + 2];
      double f3 = (double)xs[j + 3] - (double)e[j + 3];
      d0 = fma(f0, f0, d0); d1 = fma(f1, f1, d1);
      d2 = fma(f2, f2, d2); d3 = fma(f3, f3, d3);
    }
    double d = (d0 + d1) + (d2 + d3);
    if (lt2d(d, k, b1, k1)) { b2 = b1; k2 = k1; b1 = d; k1 = k; }
    else if (lt2d(d, k, b2, k2)) { b2 = d; k2 = k; }
  }
  for (int w = 1; w < 64; w <<= 1) {
    double o1 = __shfl_xor(b1, w), o2 = __shfl_xor(b2, w);
    int ok1 = __shfl_xor(k1, w), ok2 = __shfl_xor(k2, w);
    merge_top2d(b1, k1, b2, k2, o1, ok1, o2, ok2);
  }
  int lane = t & 63, wv = t >> 6;
  if (lane == 0) { rb1[wv] = b1; rk1[wv] = k1; rb2[wv] = b2; rk2[wv] = k2; }
  __syncthreads();
  if (t == 0) {
    double m1 = rb1[0], m2 = rb2[0]; int a1 = rk1[0], a2 = rk2[0];
    for (int v = 1; v < 4; ++v)
      merge_top2d(m1, a1, m2, a2, rb1[v], rk1[v], rb2[v], rk2[v]);
    sAB[0] = a1; sAB[1] = a2;
  }
  __syncthreads();
  int A = sAB[0], B = sAB[1];
  // fp64 xe,e2 for A (warp 0) / B (warp 1); x2 (warp 2)
  if (wv < 2) {
    const float* e = cb + ((long)c * NK + (wv ? B : A)) * ND;
    double xe = 0, e2 = 0;
    for (int j = lane; j < ND; j += 64) {
      double ev = (double)e[j], xv = (double)xs[j];
      xe = fma(xv, ev, xe);
      e2 = fma(ev, ev, e2);
    }
    for (int w = 1; w < 64; w <<= 1) { xe += __shfl_xor(xe, w); e2 += __shfl_xor(e2, w); }
    if (lane == 0) { sh_xe[wv] = xe; sh_e2[wv] = e2; }
  } else if (wv == 2) {
    double x2 = 0;
    for (int j = lane; j < ND; j += 64) { double xv = (double)xs[j]; x2 = fma(xv, xv, x2); }
    for (int w = 1; w < 64; w <<= 1) x2 += __shfl_xor(x2, w);
    if (lane == 0) sh_x2 = x2;
  }
  __syncthreads();
  if (t == 0) {
    float x2f = (float)sh_x2;
    float e2A = (float)sh_e2[0], e2B = (float)sh_e2[1];
    double xeA = sh_xe[0], xeB = sh_xe[1];
    const double JX = 3.0e-6;          // plausible np xe build-error bound
    int cntA = 0, cntB = 0;
    for (int u = -3; u <= 3; ++u) {    // sample quantizer phase via x2 +/- ulps
      float x2c = __uint_as_float((u32)((int)__float_as_uint(x2f) + u));
      for (int j = 0; j < 4; ++j) {    // j=0,1: no jitter (double weight); 2,3: +/-JX
        double jit = (j == 2) ? JX : (j == 3) ? -JX : 0.0;
        float xeAf = (float)(xeA + jit);
        float xeBf = (float)(xeB - jit);
        float DA = __fadd_rn(__fsub_rn(x2c, __fmul_rn(2.0f, xeAf)), e2A);
        float DB = __fadd_rn(__fsub_rn(x2c, __fmul_rn(2.0f, xeBf)), e2B);
        bool pickA = (DA < DB) || (DA == DB && A < B);   // fp32 tie -> np.argmin first index
        if (pickA) ++cntA; else ++cntB;
      }
    }
    int pick = (cntA > cntB) ? A : (cntB > cntA) ? B : (A < B ? A : B);
    fidx[row] = pick;
  }
}

// ---------------- gather x_q_st, loss, counts, embed_ind ----------------
__global__ __launch_bounds__(256) void gather_kernel(
    const float* __restrict__ x, const float* __restrict__ cb,
    const int* __restrict__ fidx, float* __restrict__ out,
    int* __restrict__ counts, double* __restrict__ loss) {
  int bid = blockIdx.x;                // b*NC + c
  int c = bid & (NC - 1);
  int t = threadIdx.x;
  int k = fidx[bid];
  const float* e  = cb + ((long)c * NK + k) * ND + t * 4;
  const float* xv = x + (long)bid * ND + t * 4;
  float* dst = out + (long)bid * ND + t * 4;
  float4 ev = *(const float4*)e;
  float4 x4 = *(const float4*)xv;
  float d0 = ev.x - x4.x, d1 = ev.y - x4.y, d2 = ev.z - x4.z, d3 = ev.w - x4.w;
  float4 o; o.x = x4.x + d0; o.y = x4.y + d1; o.z = x4.z + d2; o.w = x4.w + d3;
  *(float4*)dst = o;
  float ls = d0*d0 + d1*d1 + d2*d2 + d3*d3;
#pragma unroll
  for (int w = 1; w < 64; w <<= 1) ls += __shfl_xor(ls, w);
  __shared__ float part[4];
  if ((t & 63) == 0) part[t >> 6] = ls;
  __syncthreads();
  if (t == 0) {
    double tot = (double)part[0] + (double)part[1] + (double)part[2] + (double)part[3];
    atomicAdd(&loss[c], tot);
    out[XQ_OFF + 2 + bid] = (float)k;
    atomicAdd(&counts[c * NK + k], 1);
  }
}

__global__ __launch_bounds__(256) void finalize_kernel(const int* __restrict__ counts,
                                                       const double* __restrict__ loss,
                                                       float* __restrict__ out) {
  int t = threadIdx.x;
  int cnt = 0;
  for (int i = t; i < NC * NK; i += 256) cnt += (counts[i] == 0) ? 1 : 0;
#pragma unroll
  for (int w = 1; w < 64; w <<= 1) cnt += __shfl_xor(cnt, w);
  __shared__ int part[4];
  if ((t & 63) == 0) part[t >> 6] = cnt;
  __syncthreads();
  if (t == 0) {
    int total = part[0] + part[1] + part[2] + part[3];
    double s = loss[0] + loss[1] + loss[2] + loss[3];
    out[XQ_OFF + 0] = (float)(1.25 * s / (double)((long)NB * ND));
    out[XQ_OFF + 1] = (float)total;
  }
}

extern "C" void kernel_launch(void* const* d_in, const int* in_sizes, int n_in,
                              void* d_out, int out_size, void* d_ws, size_t ws_size,
                              hipStream_t stream) {
  (void)in_sizes; (void)n_in; (void)out_size;
  const float* x  = (const float*)d_in[0];
  const float* cb = (const float*)d_in[1];
  float* out = (float*)d_out;
  char* ws = (char*)d_ws;

  size_t sz_half = (size_t)NC * NK * ND * sizeof(f16);   // 64 MiB each
  f16* cbh = (f16*)(ws + 0 * sz_half);
  f16* cbl = (f16*)(ws + 1 * sz_half);
  f16* xh  = (f16*)(ws + 2 * sz_half);
  f16* xl  = (f16*)(ws + 3 * sz_half);
  size_t off = 4 * sz_half;
  float* e2np = (float*)(ws + off); off += (size_t)NC * NK * 4;
  u64*  wsA   = (u64*)(ws + off);   off += (size_t)NB * NC * 4 * 8;
  u64*  wsB   = (u64*)(ws + off);   off += (size_t)NB * NC * 4 * 8;
  int*  fidx  = (int*)(ws + off);   off += (size_t)NB * NC * 4;
  int*  counts= (int*)(ws + off);   off += (size_t)NC * NK * 4;
  double* loss= (double*)(ws + off);off += NC * 8;
  if (ws_size < off) {
    fprintf(stderr, "kernel_launch: workspace too small: need %zu, have %zu\n", off, ws_size);
    return;
  }

  hipMemsetAsync(counts, 0, (size_t)NC * NK * 4, stream);
  hipMemsetAsync(loss, 0, NC * 8, stream);

  prep_split<<<NC * NT * KT, 256, 0, stream>>>(cb, cbh, cbl, 0);
  prep_split<<<NC * MT * KT, 256, 0, stream>>>(x, xh, xl, 1);
  row2_np<<<(NC * NK) / 32, 256, 0, stream>>>(cb, e2np);
  vq_gemm<<<NC * MT * 2, 256, 0, stream>>>(xh, xl, cbh, cbl, e2np, wsA, wsB);
  rescue_kernel<<<NB * NC, 256, 0, stream>>>(x, cb, wsA, wsB, fidx);
  gather_kernel<<<NB * NC, 256, 0, stream>>>(x, cb, fidx, out, counts, loss);
  finalize_kernel<<<1, 256, 0, stream>>>(counts, loss, out);
}

// Round 6
// 2537.653 us; speedup vs baseline: 1.6509x; 1.6509x over previous
//
#include <hip/hip_runtime.h>
#include <cstdio>
#include <cstdint>

typedef _Float16 f16;
typedef __attribute__((ext_vector_type(8))) _Float16 f16x8;
typedef __attribute__((ext_vector_type(4))) float f32x4;
typedef unsigned int u32;
typedef unsigned long long u64;

static constexpr int NB = 8192;
static constexpr int NC = 4;
static constexpr int NK = 8192;
static constexpr int ND = 1024;
static constexpr int BM = 128, BN = 128, BK = 32;
static constexpr int MT = NB / BM;   // 64
static constexpr int NT = NK / BN;   // 64
static constexpr int KT = ND / BK;   // 32
static constexpr float SCALE_X = 1024.f;   // 2^10
static constexpr float SCALE_E = 4096.f;   // 2^12
static constexpr float RESCUE_THR = 1.4e-4f;   // score-gap; = 2.8e-4 dist-gap
static constexpr int MAXF = 1024;   // max flagged rows (expected ~20)
static constexpr int TPR  = 128;    // scan tasks per flagged row
static constexpr int CPT  = 64;     // codes per task (TPR*CPT = NK)

static constexpr long XQ_OFF = (long)NB * NC * ND;   // 33554432

__device__ __forceinline__ void glds16(const void* g, void* l) {
  __builtin_amdgcn_global_load_lds((const __attribute__((address_space(1))) u32*)g,
                                   (__attribute__((address_space(3))) u32*)l, 16, 0, 0);
}

__device__ __forceinline__ bool lt2(float s, int i, float so, int io) {
  return s < so || (s == so && i < io);
}
__device__ __forceinline__ void merge_top2(float& s1, int& i1, float& s2, int& i2,
                                           float o1, int oi1, float o2, int oi2) {
  float a1, b1; int ai1, bi1;
  if (lt2(o1, oi1, s1, i1)) { a1 = o1; ai1 = oi1; b1 = s1; bi1 = i1; }
  else                      { a1 = s1; ai1 = i1;  b1 = o1; bi1 = oi1; }
  float c2 = s2; int ci2 = i2;
  if (lt2(o2, oi2, c2, ci2)) { c2 = o2; ci2 = oi2; }
  if (lt2(b1, bi1, c2, ci2)) { c2 = b1; ci2 = bi1; }
  s1 = a1; i1 = ai1; s2 = c2; i2 = ci2;
}
__device__ __forceinline__ bool lt2d(double s, int i, double so, int io) {
  return s < so || (s == so && i < io);
}
__device__ __forceinline__ void merge_top2d(double& s1, int& i1, double& s2, int& i2,
                                            double o1, int oi1, double o2, int oi2) {
  double a1, b1; int ai1, bi1;
  if (lt2d(o1, oi1, s1, i1)) { a1 = o1; ai1 = oi1; b1 = s1; bi1 = i1; }
  else                       { a1 = s1; ai1 = i1;  b1 = o1; bi1 = oi1; }
  double c2 = s2; int ci2 = i2;
  if (lt2d(o2, oi2, c2, ci2)) { c2 = o2; ci2 = oi2; }
  if (lt2d(b1, bi1, c2, ci2)) { c2 = b1; ci2 = bi1; }
  s1 = a1; i1 = ai1; s2 = c2; i2 = ci2;
}

// ---------------- prep: fp32 -> (hi,lo) fp16 split, GEMM-tiled layout ----------------
__global__ __launch_bounds__(256) void prep_split(const float* __restrict__ src,
                                                  f16* __restrict__ hi, f16* __restrict__ lo,
                                                  int is_x) {
  int bid = blockIdx.x;
  int kt = bid & (KT - 1);
  int tile = (bid >> 5) & 63;
  int c = bid >> 11;
  int t = threadIdx.x;
  int row = t >> 1, h = t & 1;
  long srow = is_x ? ((long)(tile * BM + row) * NC + c)
                   : ((long)c * NK + tile * BN + row);
  const float* s = src + srow * ND + kt * BK + h * 16;
  float sc = is_x ? SCALE_X : SCALE_E;
  float vbuf[16];
#pragma unroll
  for (int j = 0; j < 4; ++j) {
    float4 v = *(const float4*)(s + j * 4);
    vbuf[j*4+0]=v.x; vbuf[j*4+1]=v.y; vbuf[j*4+2]=v.z; vbuf[j*4+3]=v.w;
  }
  f16 hv[16], lv[16];
#pragma unroll
  for (int j = 0; j < 16; ++j) {
    float v = vbuf[j] * sc;
    f16 hh = (f16)v;
    hv[j] = hh;
    lv[j] = (f16)(v - (float)hh);
  }
  long tb = (long)bid * (BM * BK);
#pragma unroll
  for (int kb = 0; kb < 2; ++kb) {
    long off = tb + (((long)(h*2 + kb) * BM + row) << 3);
    f16x8 hx, lx;
#pragma unroll
    for (int e = 0; e < 8; ++e) { hx[e] = hv[kb*8+e]; lx[e] = lv[kb*8+e]; }
    *(f16x8*)(hi + off) = hx;
    *(f16x8*)(lo + off) = lx;
  }
}

// ---------------- e2 (fp32 — only used inside the monotone score) --------
__global__ __launch_bounds__(256) void row2_np(const float* __restrict__ src,
                                               float* __restrict__ dst) {
  int row = blockIdx.x * 32 + (threadIdx.x >> 3);
  int blk = threadIdx.x & 7;
  const float* p = src + (long)row * ND + blk * 128;
  float r[8];
  float4 a0 = *(const float4*)(p);
  float4 a1 = *(const float4*)(p + 4);
  r[0] = a0.x*a0.x; r[1] = a0.y*a0.y; r[2] = a0.z*a0.z; r[3] = a0.w*a0.w;
  r[4] = a1.x*a1.x; r[5] = a1.y*a1.y; r[6] = a1.z*a1.z; r[7] = a1.w*a1.w;
#pragma unroll
  for (int i = 1; i < 16; ++i) {
    float4 b0 = *(const float4*)(p + i * 8);
    float4 b1 = *(const float4*)(p + i * 8 + 4);
    r[0] += b0.x*b0.x; r[1] += b0.y*b0.y; r[2] += b0.z*b0.z; r[3] += b0.w*b0.w;
    r[4] += b1.x*b1.x; r[5] += b1.y*b1.y; r[6] += b1.z*b1.z; r[7] += b1.w*b1.w;
  }
  float res = ((r[0]+r[1])+(r[2]+r[3])) + ((r[4]+r[5])+(r[6]+r[7]));
  res += __shfl_xor(res, 1);
  res += __shfl_xor(res, 2);
  res += __shfl_xor(res, 4);
  if (blk == 0) dst[row] = res;
}

// ---------------- fused split-GEMM + running top-2 of score = 0.5*e2 - xe ----------
__global__ __launch_bounds__(256, 2) void vq_gemm(
    const f16* __restrict__ xh, const f16* __restrict__ xl,
    const f16* __restrict__ cbh, const f16* __restrict__ cbl,
    const float* __restrict__ e2np,
    u64* __restrict__ wsA, u64* __restrict__ wsB) {
  __shared__ char smem[65536];
  int bid = blockIdx.x;
  int nh = bid & 1;
  int mt = (bid >> 1) & (MT - 1);
  int c  = bid >> 7;
  int tid = threadIdx.x;
  int lane = tid & 63;
  int wid = tid >> 6;
  int g = lane >> 4, r16 = lane & 15;
  int wm = wid >> 1, wn = wid & 1;
  int m0 = wm * 64, n0 = wn * 64;
  int nt0 = nh * (NT / 2);

  const f16* aH = xh + ((long)(c * MT + mt) * KT) * (BM * BK);
  const f16* aL = xl + ((long)(c * MT + mt) * KT) * (BM * BK);

  f32x4 acc[4][4];
#pragma unroll
  for (int i = 0; i < 4; ++i)
#pragma unroll
    for (int j = 0; j < 4; ++j) acc[i][j] = f32x4{0.f, 0.f, 0.f, 0.f};

  float run_s[4][4], run_s2[4][4];
  int run_i[4][4], run_i2[4][4];
#pragma unroll
  for (int i = 0; i < 4; ++i)
#pragma unroll
    for (int j = 0; j < 4; ++j) {
      run_s[i][j] = 1e30f; run_s2[i][j] = 1e30f;
      run_i[i][j] = 0x7fffffff; run_i2[i][j] = 0x7fffffff;
    }

  int wb  = (tid & 192) << 4;
  int t16 = tid << 4;

  auto stage = [&](int t) {
    int ntl = t >> 5;
    int kt  = t & 31;
    int nt  = nt0 + ntl;
    char* sb = smem + ((t & 1) << 15);
    const char* gah = (const char*)(aH + (long)kt * (BM * BK)) + t16;
    const char* gal = (const char*)(aL + (long)kt * (BM * BK)) + t16;
    const char* gbh = (const char*)(cbh + ((long)(c * NT + nt) * KT + kt) * (BN * BK)) + t16;
    const char* gbl = (const char*)(cbl + ((long)(c * NT + nt) * KT + kt) * (BN * BK)) + t16;
    char* l0 = sb + wb;
    glds16(gah,        l0);
    glds16(gah + 4096, l0 + 4096);
    glds16(gal,        l0 + 8192);
    glds16(gal + 4096, l0 + 12288);
    glds16(gbh,        l0 + 16384);
    glds16(gbh + 4096, l0 + 20480);
    glds16(gbl,        l0 + 24576);
    glds16(gbl + 4096, l0 + 28672);
  };

  stage(0);
  const int TSTEPS = (NT / 2) * KT;   // 1024
  for (int t = 0; t < TSTEPS; ++t) {
    __syncthreads();
    if (t + 1 < TSTEPS) stage(t + 1);
    const char* base = smem + ((t & 1) << 15);
    f16x8 fa_h[4], fa_l[4], fb_h[4], fb_l[4];
#pragma unroll
    for (int mf = 0; mf < 4; ++mf) {
      int off = (g * BM + m0 + mf * 16 + r16) << 4;
      fa_h[mf] = *(const f16x8*)(base + off);
      fa_l[mf] = *(const f16x8*)(base + 8192 + off);
    }
#pragma unroll
    for (int nf = 0; nf < 4; ++nf) {
      int off = (g * BN + n0 + nf * 16 + r16) << 4;
      fb_h[nf] = *(const f16x8*)(base + 16384 + off);
      fb_l[nf] = *(const f16x8*)(base + 24576 + off);
    }
#pragma unroll
    for (int mf = 0; mf < 4; ++mf)
#pragma unroll
      for (int nf = 0; nf < 4; ++nf) {
        acc[mf][nf] = __builtin_amdgcn_mfma_f32_16x16x32_f16(fa_h[mf], fb_h[nf], acc[mf][nf], 0, 0, 0);
        acc[mf][nf] = __builtin_amdgcn_mfma_f32_16x16x32_f16(fa_h[mf], fb_l[nf], acc[mf][nf], 0, 0, 0);
        acc[mf][nf] = __builtin_amdgcn_mfma_f32_16x16x32_f16(fa_l[mf], fb_h[nf], acc[mf][nf], 0, 0, 0);
      }

    if ((t & 31) == 31) {
      int nt = nt0 + (t >> 5);
      float he2[4]; int col[4];
#pragma unroll
      for (int nf = 0; nf < 4; ++nf) {
        col[nf] = nt * BN + n0 + nf * 16 + r16;
        he2[nf] = 0.5f * e2np[c * NK + col[nf]];
      }
#pragma unroll
      for (int mf = 0; mf < 4; ++mf)
#pragma unroll
        for (int q = 0; q < 4; ++q) {
          float s1 = __fmaf_rn(acc[mf][0][q], -0x1p-22f, he2[0]);
          int i1 = col[0];
          float s2 = 1e30f; int i2 = 0x7fffffff;
#pragma unroll
          for (int nf = 1; nf < 4; ++nf) {
            float sv = __fmaf_rn(acc[mf][nf][q], -0x1p-22f, he2[nf]);
            int ci = col[nf];
            if (lt2(sv, ci, s1, i1)) { s2 = s1; i2 = i1; s1 = sv; i1 = ci; }
            else if (lt2(sv, ci, s2, i2)) { s2 = sv; i2 = ci; }
          }
#pragma unroll
          for (int w = 1; w < 16; w <<= 1) {
            float o1 = __shfl_xor(s1, w);
            int  oi1 = __shfl_xor(i1, w);
            float o2 = __shfl_xor(s2, w);
            int  oi2 = __shfl_xor(i2, w);
            merge_top2(s1, i1, s2, i2, o1, oi1, o2, oi2);
          }
          merge_top2(run_s[mf][q], run_i[mf][q], run_s2[mf][q], run_i2[mf][q],
                     s1, i1, s2, i2);
        }
#pragma unroll
      for (int mf = 0; mf < 4; ++mf)
#pragma unroll
        for (int nf = 0; nf < 4; ++nf)
          acc[mf][nf] = f32x4{0.f, 0.f, 0.f, 0.f};
    }
  }

  if (r16 == 0) {
    int slot = nh * 2 + wn;
#pragma unroll
    for (int mf = 0; mf < 4; ++mf)
#pragma unroll
      for (int q = 0; q < 4; ++q) {
        int brow = mt * BM + m0 + mf * 16 + g * 4 + q;
        long idx = ((long)brow * NC + c) * 4 + slot;
        wsA[idx] = ((u64)__float_as_uint(run_s[mf][q])  << 32) | (u32)run_i[mf][q];
        wsB[idx] = ((u64)__float_as_uint(run_s2[mf][q]) << 32) | (u32)run_i2[mf][q];
      }
  }
}

// ---------------- rescue stage 1: flag + compact ----------------
__global__ __launch_bounds__(256) void flag_collect(
    const u64* __restrict__ wsA, const u64* __restrict__ wsB,
    int* __restrict__ fidx, int* __restrict__ flaglist, int* __restrict__ nflag) {
  int row = blockIdx.x * 256 + threadIdx.x;
  if (row >= NB * NC) return;
  float g1 = 1e30f, g2 = 1e30f; int gi1 = 0x7fffffff, gi2 = 0x7fffffff;
  for (int s = 0; s < 4; ++s) {
    u64 a = wsA[(long)row * 4 + s];
    u64 b = wsB[(long)row * 4 + s];
    merge_top2(g1, gi1, g2, gi2,
               __uint_as_float((u32)(a >> 32)), (int)(u32)(a & 0xffffffffu),
               __uint_as_float((u32)(b >> 32)), (int)(u32)(b & 0xffffffffu));
  }
  if (__fsub_rn(g2, g1) < RESCUE_THR) {
    int idx = atomicAdd(nflag, 1);
    if (idx < MAXF) flaglist[idx] = row;
    else fidx[row] = gi1;     // overflow fallback (practically impossible)
  } else {
    fidx[row] = gi1;
  }
}

// ---------------- rescue stage 2: distributed fp64 scan, per-task top-2 ----------------
// grid 1024 x 256 = 4096 waves; wave-task = (flagged row, 64-code chunk), coalesced reads
__global__ __launch_bounds__(256) void rescue_scan(
    const float* __restrict__ x, const float* __restrict__ cb,
    const int* __restrict__ flaglist, const int* __restrict__ nflag,
    double* __restrict__ pb1, double* __restrict__ pb2,
    int* __restrict__ pk1, int* __restrict__ pk2) {
  int nf = *nflag; if (nf > MAXF) nf = MAXF;
  int ntask = nf * TPR;
  int wv = blockIdx.x * 4 + (threadIdx.x >> 6);
  int lane = threadIdx.x & 63;
  for (int task = wv; task < ntask; task += 4096) {
    int fi = task >> 7, ch = task & (TPR - 1);
    int row = flaglist[fi];
    int c = row & (NC - 1);
    const float* xr = x + (long)row * ND + lane * 4;
    float4 xv0 = *(const float4*)(xr);
    float4 xv1 = *(const float4*)(xr + 256);
    float4 xv2 = *(const float4*)(xr + 512);
    float4 xv3 = *(const float4*)(xr + 768);
    double b1 = 1e300, b2 = 1e300; int k1 = 0x7fffffff, k2 = 0x7fffffff;
    const float* eb = cb + ((long)c * NK + ch * CPT) * ND + lane * 4;
    for (int kk = 0; kk < CPT; ++kk) {
      const float* e = eb + (long)kk * ND;
      float4 e0 = *(const float4*)(e);
      float4 e1 = *(const float4*)(e + 256);
      float4 e2v = *(const float4*)(e + 512);
      float4 e3 = *(const float4*)(e + 768);
      double d = 0.0;
      double f;
      f = (double)xv0.x - (double)e0.x;  d = fma(f, f, d);
      f = (double)xv0.y - (double)e0.y;  d = fma(f, f, d);
      f = (double)xv0.z - (double)e0.z;  d = fma(f, f, d);
      f = (double)xv0.w - (double)e0.w;  d = fma(f, f, d);
      f = (double)xv1.x - (double)e1.x;  d = fma(f, f, d);
      f = (double)xv1.y - (double)e1.y;  d = fma(f, f, d);
      f = (double)xv1.z - (double)e1.z;  d = fma(f, f, d);
      f = (double)xv1.w - (double)e1.w;  d = fma(f, f, d);
      f = (double)xv2.x - (double)e2v.x; d = fma(f, f, d);
      f = (double)xv2.y - (double)e2v.y; d = fma(f, f, d);
      f = (double)xv2.z - (double)e2v.z; d = fma(f, f, d);
      f = (double)xv2.w - (double)e2v.w; d = fma(f, f, d);
      f = (double)xv3.x - (double)e3.x;  d = fma(f, f, d);
      f = (double)xv3.y - (double)e3.y;  d = fma(f, f, d);
      f = (double)xv3.z - (double)e3.z;  d = fma(f, f, d);
      f = (double)xv3.w - (double)e3.w;  d = fma(f, f, d);
#pragma unroll
      for (int w = 1; w < 64; w <<= 1) d += __shfl_xor(d, w);
      int k = ch * CPT + kk;
      if (lt2d(d, k, b1, k1)) { b2 = b1; k2 = k1; b1 = d; k1 = k; }
      else if (lt2d(d, k, b2, k2)) { b2 = d; k2 = k; }
    }
    if (lane == 0) { pb1[task] = b1; pb2[task] = b2; pk1[task] = k1; pk2[task] = k2; }
  }
}

// ---------------- rescue stage 3: merge partials + np-quantization tie verdict ------
__global__ __launch_bounds__(256) void rescue_verdict(
    const float* __restrict__ x, const float* __restrict__ cb,
    const int* __restrict__ flaglist, const int* __restrict__ nflag,
    const double* __restrict__ pb1, const double* __restrict__ pb2,
    const int* __restrict__ pk1, const int* __restrict__ pk2,
    int* __restrict__ fidx) {
  int nf = *nflag; if (nf > MAXF) nf = MAXF;
  int fi = blockIdx.x;
  if (fi >= nf) return;
  int row = flaglist[fi];
  int c = row & (NC - 1);
  int t = threadIdx.x;
  __shared__ float xs[ND];
  __shared__ int sAB[2];
  __shared__ double sh_xe[2], sh_e2[2], sh_x2;
  for (int i = t; i < ND; i += 256) xs[i] = x[(long)row * ND + i];
  if (t == 0) {
    double m1 = 1e300, m2 = 1e300; int a1 = 0x7fffffff, a2 = 0x7fffffff;
    for (int p = 0; p < TPR; ++p) {
      long pi = (long)fi * TPR + p;
      merge_top2d(m1, a1, m2, a2, pb1[pi], pk1[pi], pb2[pi], pk2[pi]);
    }
    sAB[0] = a1; sAB[1] = a2;
  }
  __syncthreads();
  int A = sAB[0], B = sAB[1];
  int lane = t & 63, wvv = t >> 6;
  if (wvv < 2) {
    const float* e = cb + ((long)c * NK + (wvv ? B : A)) * ND;
    double xe = 0, e2 = 0;
    for (int j = lane; j < ND; j += 64) {
      double ev = (double)e[j], xv = (double)xs[j];
      xe = fma(xv, ev, xe);
      e2 = fma(ev, ev, e2);
    }
    for (int w = 1; w < 64; w <<= 1) { xe += __shfl_xor(xe, w); e2 += __shfl_xor(e2, w); }
    if (lane == 0) { sh_xe[wvv] = xe; sh_e2[wvv] = e2; }
  } else if (wvv == 2) {
    double x2 = 0;
    for (int j = lane; j < ND; j += 64) { double xv = (double)xs[j]; x2 = fma(xv, xv, x2); }
    for (int w = 1; w < 64; w <<= 1) x2 += __shfl_xor(x2, w);
    if (lane == 0) sh_x2 = x2;
  }
  __syncthreads();
  if (t == 0) {
    float x2f = (float)sh_x2;
    float e2A = (float)sh_e2[0], e2B = (float)sh_e2[1];
    double xeA = sh_xe[0], xeB = sh_xe[1];
    const double JX = 3.0e-6;          // plausible np xe build-error bound
    int cntA = 0, cntB = 0;
    for (int u = -3; u <= 3; ++u) {    // sample quantizer phase via x2 +/- ulps
      float x2c = __uint_as_float((u32)((int)__float_as_uint(x2f) + u));
      for (int j = 0; j < 4; ++j) {    // j=0,1: no jitter (double weight); 2,3: +/-JX
        double jit = (j == 2) ? JX : (j == 3) ? -JX : 0.0;
        float xeAf = (float)(xeA + jit);
        float xeBf = (float)(xeB - jit);
        float DA = __fadd_rn(__fsub_rn(x2c, __fmul_rn(2.0f, xeAf)), e2A);
        float DB = __fadd_rn(__fsub_rn(x2c, __fmul_rn(2.0f, xeBf)), e2B);
        bool pickA = (DA < DB) || (DA == DB && A < B);   // fp32 tie -> np.argmin first index
        if (pickA) ++cntA; else ++cntB;
      }
    }
    int pick = (cntA > cntB) ? A : (cntB > cntA) ? B : (A < B ? A : B);
    fidx[row] = pick;
  }
}

// ---------------- gather x_q_st, loss, counts, embed_ind ----------------
__global__ __launch_bounds__(256) void gather_kernel(
    const float* __restrict__ x, const float* __restrict__ cb,
    const int* __restrict__ fidx, float* __restrict__ out,
    int* __restrict__ counts, double* __restrict__ loss) {
  int bid = blockIdx.x;                // b*NC + c
  int c = bid & (NC - 1);
  int t = threadIdx.x;
  int k = fidx[bid];
  const float* e  = cb + ((long)c * NK + k) * ND + t * 4;
  const float* xv = x + (long)bid * ND + t * 4;
  float* dst = out + (long)bid * ND + t * 4;
  float4 ev = *(const float4*)e;
  float4 x4 = *(const float4*)xv;
  float d0 = ev.x - x4.x, d1 = ev.y - x4.y, d2 = ev.z - x4.z, d3 = ev.w - x4.w;
  float4 o; o.x = x4.x + d0; o.y = x4.y + d1; o.z = x4.z + d2; o.w = x4.w + d3;
  *(float4*)dst = o;
  float ls = d0*d0 + d1*d1 + d2*d2 + d3*d3;
#pragma unroll
  for (int w = 1; w < 64; w <<= 1) ls += __shfl_xor(ls, w);
  __shared__ float part[4];
  if ((t & 63) == 0) part[t >> 6] = ls;
  __syncthreads();
  if (t == 0) {
    double tot = (double)part[0] + (double)part[1] + (double)part[2] + (double)part[3];
    atomicAdd(&loss[c], tot);
    out[XQ_OFF + 2 + bid] = (float)k;
    atomicAdd(&counts[c * NK + k], 1);
  }
}

__global__ __launch_bounds__(256) void finalize_kernel(const int* __restrict__ counts,
                                                       const double* __restrict__ loss,
                                                       float* __restrict__ out) {
  int t = threadIdx.x;
  int cnt = 0;
  for (int i = t; i < NC * NK; i += 256) cnt += (counts[i] == 0) ? 1 : 0;
#pragma unroll
  for (int w = 1; w < 64; w <<= 1) cnt += __shfl_xor(cnt, w);
  __shared__ int part[4];
  if ((t & 63) == 0) part[t >> 6] = cnt;
  __syncthreads();
  if (t == 0) {
    int total = part[0] + part[1] + part[2] + part[3];
    double s = loss[0] + loss[1] + loss[2] + loss[3];
    out[XQ_OFF + 0] = (float)(1.25 * s / (double)((long)NB * ND));
    out[XQ_OFF + 1] = (float)total;
  }
}

extern "C" void kernel_launch(void* const* d_in, const int* in_sizes, int n_in,
                              void* d_out, int out_size, void* d_ws, size_t ws_size,
                              hipStream_t stream) {
  (void)in_sizes; (void)n_in; (void)out_size;
  const float* x  = (const float*)d_in[0];
  const float* cb = (const float*)d_in[1];
  float* out = (float*)d_out;
  char* ws = (char*)d_ws;

  size_t sz_half = (size_t)NC * NK * ND * sizeof(f16);   // 64 MiB each
  f16* cbh = (f16*)(ws + 0 * sz_half);
  f16* cbl = (f16*)(ws + 1 * sz_half);
  f16* xh  = (f16*)(ws + 2 * sz_half);
  f16* xl  = (f16*)(ws + 3 * sz_half);
  size_t off = 4 * sz_half;
  float* e2np = (float*)(ws + off); off += (size_t)NC * NK * 4;
  u64*  wsA   = (u64*)(ws + off);   off += (size_t)NB * NC * 4 * 8;
  u64*  wsB   = (u64*)(ws + off);   off += (size_t)NB * NC * 4 * 8;
  int*  fidx  = (int*)(ws + off);   off += (size_t)NB * NC * 4;
  int*  counts= (int*)(ws + off);   off += (size_t)NC * NK * 4;
  double* loss= (double*)(ws + off);off += NC * 8;
  if (ws_size < off) {
    fprintf(stderr, "kernel_launch: workspace too small: need %zu, have %zu\n", off, ws_size);
    return;
  }
  // rescue scratch ALIASES cbh/cbl region (dead after vq_gemm) — zero ws growth
  char* rs = ws;
  int*    nflag    = (int*)rs;                          // 256 B slot
  int*    flaglist = (int*)(rs + 256);                  // MAXF*4
  double* pb1      = (double*)(rs + 256 + MAXF * 4);
  double* pb2      = pb1 + (size_t)MAXF * TPR;          // 1 MiB each
  int*    pk1      = (int*)(pb2 + (size_t)MAXF * TPR);
  int*    pk2      = pk1 + (size_t)MAXF * TPR;          // 0.5 MiB each

  hipMemsetAsync(counts, 0, (size_t)NC * NK * 4, stream);
  hipMemsetAsync(loss, 0, NC * 8, stream);

  prep_split<<<NC * NT * KT, 256, 0, stream>>>(cb, cbh, cbl, 0);
  prep_split<<<NC * MT * KT, 256, 0, stream>>>(x, xh, xl, 1);
  row2_np<<<(NC * NK) / 32, 256, 0, stream>>>(cb, e2np);
  vq_gemm<<<NC * MT * 2, 256, 0, stream>>>(xh, xl, cbh, cbl, e2np, wsA, wsB);

  hipMemsetAsync(nflag, 0, sizeof(int), stream);        // after vq_gemm (aliased region)
  flag_collect<<<(NB * NC) / 256, 256, 0, stream>>>(wsA, wsB, fidx, flaglist, nflag);
  rescue_scan<<<1024, 256, 0, stream>>>(x, cb, flaglist, nflag, pb1, pb2, pk1, pk2);
  rescue_verdict<<<MAXF, 256, 0, stream>>>(x, cb, flaglist, nflag, pb1, pb2, pk1, pk2, fidx);

  gather_kernel<<<NB * NC, 256, 0, stream>>>(x, cb, fidx, out, counts, loss);
  finalize_kernel<<<1, 256, 0, stream>>>(counts, loss, out);
}

// Round 7
// 2411.364 us; speedup vs baseline: 1.7373x; 1.0524x over previous
//
#include <hip/hip_runtime.h>
#include <cstdio>
#include <cstdint>

typedef _Float16 f16;
typedef __attribute__((ext_vector_type(8))) _Float16 f16x8;
typedef __attribute__((ext_vector_type(4))) float f32x4;
typedef unsigned int u32;
typedef unsigned long long u64;

static constexpr int NB = 8192;
static constexpr int NC = 4;
static constexpr int NK = 8192;
static constexpr int ND = 1024;
static constexpr int BM = 128, BN = 128, BK = 32;
static constexpr int MT = NB / BM;   // 64
static constexpr int NT = NK / BN;   // 64
static constexpr int KT = ND / BK;   // 32
static constexpr float SCALE_X = 1024.f;   // 2^10
static constexpr float SCALE_E = 4096.f;   // 2^12
static constexpr float RESCUE_THR = 1.4e-4f;   // score-gap; = 2.8e-4 dist-gap
static constexpr int MAXF = 1024;
static constexpr int TPR  = 128;
static constexpr int CPT  = 64;

static constexpr long XQ_OFF = (long)NB * NC * ND;   // 33554432
static constexpr int BUFSZ = 49152;   // 48KB: Ah16K | Al16K | Bh8K | Bl8K

__device__ __forceinline__ void glds16(const void* g, void* l) {
  __builtin_amdgcn_global_load_lds((const __attribute__((address_space(1))) u32*)g,
                                   (__attribute__((address_space(3))) u32*)l, 16, 0, 0);
}

__device__ __forceinline__ bool lt2(float s, int i, float so, int io) {
  return s < so || (s == so && i < io);
}
__device__ __forceinline__ void merge_top2(float& s1, int& i1, float& s2, int& i2,
                                           float o1, int oi1, float o2, int oi2) {
  float a1, b1; int ai1, bi1;
  if (lt2(o1, oi1, s1, i1)) { a1 = o1; ai1 = oi1; b1 = s1; bi1 = i1; }
  else                      { a1 = s1; ai1 = i1;  b1 = o1; bi1 = oi1; }
  float c2 = s2; int ci2 = i2;
  if (lt2(o2, oi2, c2, ci2)) { c2 = o2; ci2 = oi2; }
  if (lt2(b1, bi1, c2, ci2)) { c2 = b1; ci2 = bi1; }
  s1 = a1; i1 = ai1; s2 = c2; i2 = ci2;
}
__device__ __forceinline__ bool lt2d(double s, int i, double so, int io) {
  return s < so || (s == so && i < io);
}
__device__ __forceinline__ void merge_top2d(double& s1, int& i1, double& s2, int& i2,
                                            double o1, int oi1, double o2, int oi2) {
  double a1, b1; int ai1, bi1;
  if (lt2d(o1, oi1, s1, i1)) { a1 = o1; ai1 = oi1; b1 = s1; bi1 = i1; }
  else                       { a1 = s1; ai1 = i1;  b1 = o1; bi1 = oi1; }
  double c2 = s2; int ci2 = i2;
  if (lt2d(o2, oi2, c2, ci2)) { c2 = o2; ci2 = oi2; }
  if (lt2d(b1, bi1, c2, ci2)) { c2 = b1; ci2 = bi1; }
  s1 = a1; i1 = ai1; s2 = c2; i2 = ci2;
}

// ---------------- prep: fp32 -> (hi,lo) fp16 split, GEMM-tiled layout ----------------
__global__ __launch_bounds__(256) void prep_split(const float* __restrict__ src,
                                                  f16* __restrict__ hi, f16* __restrict__ lo,
                                                  int is_x) {
  int bid = blockIdx.x;
  int kt = bid & (KT - 1);
  int tile = (bid >> 5) & 63;
  int c = bid >> 11;
  int t = threadIdx.x;
  int row = t >> 1, h = t & 1;
  long srow = is_x ? ((long)(tile * BM + row) * NC + c)
                   : ((long)c * NK + tile * BN + row);
  const float* s = src + srow * ND + kt * BK + h * 16;
  float sc = is_x ? SCALE_X : SCALE_E;
  float vbuf[16];
#pragma unroll
  for (int j = 0; j < 4; ++j) {
    float4 v = *(const float4*)(s + j * 4);
    vbuf[j*4+0]=v.x; vbuf[j*4+1]=v.y; vbuf[j*4+2]=v.z; vbuf[j*4+3]=v.w;
  }
  f16 hv[16], lv[16];
#pragma unroll
  for (int j = 0; j < 16; ++j) {
    float v = vbuf[j] * sc;
    f16 hh = (f16)v;
    hv[j] = hh;
    lv[j] = (f16)(v - (float)hh);
  }
  long tb = (long)bid * (BM * BK);
#pragma unroll
  for (int kb = 0; kb < 2; ++kb) {
    long off = tb + (((long)(h*2 + kb) * BM + row) << 3);
    f16x8 hx, lx;
#pragma unroll
    for (int e = 0; e < 8; ++e) { hx[e] = hv[kb*8+e]; lx[e] = lv[kb*8+e]; }
    *(f16x8*)(hi + off) = hx;
    *(f16x8*)(lo + off) = lx;
  }
}

// ---------------- e2 (fp32 — only used inside the monotone score) --------
__global__ __launch_bounds__(256) void row2_np(const float* __restrict__ src,
                                               float* __restrict__ dst) {
  int row = blockIdx.x * 32 + (threadIdx.x >> 3);
  int blk = threadIdx.x & 7;
  const float* p = src + (long)row * ND + blk * 128;
  float r[8];
  float4 a0 = *(const float4*)(p);
  float4 a1 = *(const float4*)(p + 4);
  r[0] = a0.x*a0.x; r[1] = a0.y*a0.y; r[2] = a0.z*a0.z; r[3] = a0.w*a0.w;
  r[4] = a1.x*a1.x; r[5] = a1.y*a1.y; r[6] = a1.z*a1.z; r[7] = a1.w*a1.w;
#pragma unroll
  for (int i = 1; i < 16; ++i) {
    float4 b0 = *(const float4*)(p + i * 8);
    float4 b1 = *(const float4*)(p + i * 8 + 4);
    r[0] += b0.x*b0.x; r[1] += b0.y*b0.y; r[2] += b0.z*b0.z; r[3] += b0.w*b0.w;
    r[4] += b1.x*b1.x; r[5] += b1.y*b1.y; r[6] += b1.z*b1.z; r[7] += b1.w*b1.w;
  }
  float res = ((r[0]+r[1])+(r[2]+r[3])) + ((r[4]+r[5])+(r[6]+r[7]));
  res += __shfl_xor(res, 1);
  res += __shfl_xor(res, 2);
  res += __shfl_xor(res, 4);
  if (blk == 0) dst[row] = res;
}

// ---------- fused split-GEMM v2: 256x128 tile, 8 waves, 3-buffer counted-vmcnt ----------
__global__ __launch_bounds__(512, 1) void vq_gemm2(
    const f16* __restrict__ xh, const f16* __restrict__ xl,
    const f16* __restrict__ cbh, const f16* __restrict__ cbl,
    const float* __restrict__ e2np,
    u64* __restrict__ wsA, u64* __restrict__ wsB) {
  __shared__ char smem[3 * BUFSZ];   // 144 KB
  int bid0 = blockIdx.x;
  int bid = (bid0 & 7) * 32 + (bid0 >> 3);   // chunked XCD swizzle (256 = 8*32, bijective)
  int nh = bid & 1;
  int mt = (bid >> 1) & 31;                  // 32 row-supertiles of 256
  int c  = bid >> 6;
  int tid = threadIdx.x;
  int lane = tid & 63;
  int wid = tid >> 6;
  int g = lane >> 4, r16 = lane & 15;
  int wm = wid >> 1, wn = wid & 1;           // wave grid 4M x 2N, wave tile 64x64
  int m0 = wm * 64, n0 = wn * 64;

  // staging: wave-uniform LDS bases (HW adds lane*16)
  int sw_kblk = wid >> 1;                    // = (tid>>7) for all lanes of this wave
  int sw_row  = (wid & 1) * 64;              // = (tid&127) - lane

  auto stageA = [&](int t, int bufi, int tb) {   // Ah,Al of row-tile mt*2+tb (2 glds)
    int kt = t & 31;
    char* sb = smem + bufi * BUFSZ;
    long chunk = ((long)(c * 64 + mt * 2 + tb) * 32 + kt) * 4096;
    const char* gh = (const char*)(xh + chunk) + tid * 16;
    const char* gl = (const char*)(xl + chunk) + tid * 16;
    int rbase = (sw_kblk * 256 + tb * 128 + sw_row) << 4;
    glds16(gh, sb + rbase);
    glds16(gl, sb + 16384 + rbase);
  };
  auto stageB = [&](int t, int bufi, int part) { // part0: Bh, part1: Bl (1 glds)
    int kt = t & 31;
    int nt = nh * 32 + (t >> 5);
    char* sb = smem + bufi * BUFSZ;
    long chunk = ((long)(c * 64 + nt) * 32 + kt) * 4096;
    const f16* src = part ? cbl : cbh;
    const char* gp = (const char*)(src + chunk) + tid * 16;
    glds16(gp, sb + 32768 + part * 8192 + ((sw_kblk * 128 + sw_row) << 4));
  };

  f32x4 acc[4][4];
#pragma unroll
  for (int i = 0; i < 4; ++i)
#pragma unroll
    for (int j = 0; j < 4; ++j) acc[i][j] = f32x4{0.f, 0.f, 0.f, 0.f};

  float run_s[4][4], run_s2[4][4];
  int run_i[4][4], run_i2[4][4];
#pragma unroll
  for (int i = 0; i < 4; ++i)
#pragma unroll
    for (int j = 0; j < 4; ++j) {
      run_s[i][j] = 1e30f; run_s2[i][j] = 1e30f;
      run_i[i][j] = 0x7fffffff; run_i2[i][j] = 0x7fffffff;
    }

  // prologue: fully stage t=0 (buf0) and t=1 (buf1) -> 12 outstanding vmem
  stageA(0, 0, 0); stageA(0, 0, 1); stageB(0, 0, 0); stageB(0, 0, 1);
  stageA(1, 1, 0); stageA(1, 1, 1); stageB(1, 1, 0); stageB(1, 1, 1);

  const int TSTEPS = 32 * KT;   // 1024
  int bi = 0;                   // t % 3
#pragma unroll 1
  for (int t = 0; t < TSTEPS; ++t) {
    if (t == TSTEPS - 1) { asm volatile("s_waitcnt vmcnt(0)" ::: "memory"); }
    else                 { asm volatile("s_waitcnt vmcnt(6)" ::: "memory"); }
    __builtin_amdgcn_s_barrier();
    __builtin_amdgcn_sched_barrier(0);   // nothing crosses the barrier (rule #18/#21)

    const char* base   = smem + bi * BUFSZ;
    const char* baseAl = base + 16384;
    const char* baseBh = base + 32768;
    const char* baseBl = base + 40960;
    int bi2 = (bi == 0) ? 2 : bi - 1;    // (t+2) % 3
    bool pf = (t + 2 < TSTEPS);

    f16x8 fbh[4], fbl[4];
#pragma unroll
    for (int nf = 0; nf < 4; ++nf) {
      int off = (g * 128 + n0 + nf * 16 + r16) << 4;
      fbh[nf] = *(const f16x8*)(baseBh + off);
      fbl[nf] = *(const f16x8*)(baseBl + off);
    }
    f16x8 fah[2], fal[2];
#pragma unroll
    for (int mf = 0; mf < 2; ++mf) {
      int off = (g * 256 + m0 + mf * 16 + r16) << 4;
      fah[mf] = *(const f16x8*)(base + off);
      fal[mf] = *(const f16x8*)(baseAl + off);
    }
    if (pf) { stageA(t + 2, bi2, 0); stageB(t + 2, bi2, 0); }
    __builtin_amdgcn_s_setprio(1);
#pragma unroll
    for (int mf = 0; mf < 2; ++mf)
#pragma unroll
      for (int nf = 0; nf < 4; ++nf) {
        acc[mf][nf] = __builtin_amdgcn_mfma_f32_16x16x32_f16(fah[mf], fbh[nf], acc[mf][nf], 0, 0, 0);
        acc[mf][nf] = __builtin_amdgcn_mfma_f32_16x16x32_f16(fah[mf], fbl[nf], acc[mf][nf], 0, 0, 0);
        acc[mf][nf] = __builtin_amdgcn_mfma_f32_16x16x32_f16(fal[mf], fbh[nf], acc[mf][nf], 0, 0, 0);
      }
    __builtin_amdgcn_s_setprio(0);
    f16x8 gah[2], gal[2];
#pragma unroll
    for (int mf = 0; mf < 2; ++mf) {
      int off = (g * 256 + m0 + (mf + 2) * 16 + r16) << 4;
      gah[mf] = *(const f16x8*)(base + off);
      gal[mf] = *(const f16x8*)(baseAl + off);
    }
    if (pf) { stageA(t + 2, bi2, 1); stageB(t + 2, bi2, 1); }
    __builtin_amdgcn_s_setprio(1);
#pragma unroll
    for (int mf = 0; mf < 2; ++mf)
#pragma unroll
      for (int nf = 0; nf < 4; ++nf) {
        acc[mf+2][nf] = __builtin_amdgcn_mfma_f32_16x16x32_f16(gah[mf], fbh[nf], acc[mf+2][nf], 0, 0, 0);
        acc[mf+2][nf] = __builtin_amdgcn_mfma_f32_16x16x32_f16(gah[mf], fbl[nf], acc[mf+2][nf], 0, 0, 0);
        acc[mf+2][nf] = __builtin_amdgcn_mfma_f32_16x16x32_f16(gal[mf], fbh[nf], acc[mf+2][nf], 0, 0, 0);
      }
    __builtin_amdgcn_s_setprio(0);

    if ((t & 31) == 31) {   // supertile epilogue: score + top-2 (e2 loads drain vmcnt, 1/32 amortized)
      int ntl = t >> 5;
      float he2[4]; int col[4];
#pragma unroll
      for (int nf = 0; nf < 4; ++nf) {
        col[nf] = nh * 4096 + ntl * 128 + n0 + nf * 16 + r16;
        he2[nf] = 0.5f * e2np[c * NK + col[nf]];
      }
#pragma unroll
      for (int mf = 0; mf < 4; ++mf)
#pragma unroll
        for (int q = 0; q < 4; ++q) {
          float s1 = __fmaf_rn(acc[mf][0][q], -0x1p-22f, he2[0]);
          int i1 = col[0];
          float s2 = 1e30f; int i2 = 0x7fffffff;
#pragma unroll
          for (int nf = 1; nf < 4; ++nf) {
            float sv = __fmaf_rn(acc[mf][nf][q], -0x1p-22f, he2[nf]);
            int ci = col[nf];
            if (lt2(sv, ci, s1, i1)) { s2 = s1; i2 = i1; s1 = sv; i1 = ci; }
            else if (lt2(sv, ci, s2, i2)) { s2 = sv; i2 = ci; }
          }
#pragma unroll
          for (int w = 1; w < 16; w <<= 1) {
            float o1 = __shfl_xor(s1, w);
            int  oi1 = __shfl_xor(i1, w);
            float o2 = __shfl_xor(s2, w);
            int  oi2 = __shfl_xor(i2, w);
            merge_top2(s1, i1, s2, i2, o1, oi1, o2, oi2);
          }
          merge_top2(run_s[mf][q], run_i[mf][q], run_s2[mf][q], run_i2[mf][q],
                     s1, i1, s2, i2);
        }
#pragma unroll
      for (int mf = 0; mf < 4; ++mf)
#pragma unroll
        for (int nf = 0; nf < 4; ++nf)
          acc[mf][nf] = f32x4{0.f, 0.f, 0.f, 0.f};
    }
    bi = (bi == 2) ? 0 : bi + 1;
  }

  if (r16 == 0) {                 // lanes 0,16,32,48 own distinct row groups
    int slot = nh * 2 + wn;
#pragma unroll
    for (int mf = 0; mf < 4; ++mf)
#pragma unroll
      for (int q = 0; q < 4; ++q) {
        int brow = mt * 256 + m0 + mf * 16 + g * 4 + q;
        long idx = ((long)brow * NC + c) * 4 + slot;
        wsA[idx] = ((u64)__float_as_uint(run_s[mf][q])  << 32) | (u32)run_i[mf][q];
        wsB[idx] = ((u64)__float_as_uint(run_s2[mf][q]) << 32) | (u32)run_i2[mf][q];
      }
  }
}

// ---------------- rescue stage 1: flag + compact ----------------
__global__ __launch_bounds__(256) void flag_collect(
    const u64* __restrict__ wsA, const u64* __restrict__ wsB,
    int* __restrict__ fidx, int* __restrict__ flaglist, int* __restrict__ nflag) {
  int row = blockIdx.x * 256 + threadIdx.x;
  if (row >= NB * NC) return;
  float g1 = 1e30f, g2 = 1e30f; int gi1 = 0x7fffffff, gi2 = 0x7fffffff;
  for (int s = 0; s < 4; ++s) {
    u64 a = wsA[(long)row * 4 + s];
    u64 b = wsB[(long)row * 4 + s];
    merge_top2(g1, gi1, g2, gi2,
               __uint_as_float((u32)(a >> 32)), (int)(u32)(a & 0xffffffffu),
               __uint_as_float((u32)(b >> 32)), (int)(u32)(b & 0xffffffffu));
  }
  if (__fsub_rn(g2, g1) < RESCUE_THR) {
    int idx = atomicAdd(nflag, 1);
    if (idx < MAXF) flaglist[idx] = row;
    else fidx[row] = gi1;
  } else {
    fidx[row] = gi1;
  }
}

// ---------------- rescue stage 2: distributed fp64 scan, per-task top-2 ----------------
__global__ __launch_bounds__(256) void rescue_scan(
    const float* __restrict__ x, const float* __restrict__ cb,
    const int* __restrict__ flaglist, const int* __restrict__ nflag,
    double* __restrict__ pb1, double* __restrict__ pb2,
    int* __restrict__ pk1, int* __restrict__ pk2) {
  int nf = *nflag; if (nf > MAXF) nf = MAXF;
  int ntask = nf * TPR;
  int wv = blockIdx.x * 4 + (threadIdx.x >> 6);
  int lane = threadIdx.x & 63;
  for (int task = wv; task < ntask; task += 4096) {
    int fi = task >> 7, ch = task & (TPR - 1);
    int row = flaglist[fi];
    int c = row & (NC - 1);
    const float* xr = x + (long)row * ND + lane * 4;
    float4 xv0 = *(const float4*)(xr);
    float4 xv1 = *(const float4*)(xr + 256);
    float4 xv2 = *(const float4*)(xr + 512);
    float4 xv3 = *(const float4*)(xr + 768);
    double b1 = 1e300, b2 = 1e300; int k1 = 0x7fffffff, k2 = 0x7fffffff;
    const float* eb = cb + ((long)c * NK + ch * CPT) * ND + lane * 4;
    for (int kk = 0; kk < CPT; ++kk) {
      const float* e = eb + (long)kk * ND;
      float4 e0 = *(const float4*)(e);
      float4 e1 = *(const float4*)(e + 256);
      float4 e2v = *(const float4*)(e + 512);
      float4 e3 = *(const float4*)(e + 768);
      double d = 0.0;
      double f;
      f = (double)xv0.x - (double)e0.x;  d = fma(f, f, d);
      f = (double)xv0.y - (double)e0.y;  d = fma(f, f, d);
      f = (double)xv0.z - (double)e0.z;  d = fma(f, f, d);
      f = (double)xv0.w - (double)e0.w;  d = fma(f, f, d);
      f = (double)xv1.x - (double)e1.x;  d = fma(f, f, d);
      f = (double)xv1.y - (double)e1.y;  d = fma(f, f, d);
      f = (double)xv1.z - (double)e1.z;  d = fma(f, f, d);
      f = (double)xv1.w - (double)e1.w;  d = fma(f, f, d);
      f = (double)xv2.x - (double)e2v.x; d = fma(f, f, d);
      f = (double)xv2.y - (double)e2v.y; d = fma(f, f, d);
      f = (double)xv2.z - (double)e2v.z; d = fma(f, f, d);
      f = (double)xv2.w - (double)e2v.w; d = fma(f, f, d);
      f = (double)xv3.x - (double)e3.x;  d = fma(f, f, d);
      f = (double)xv3.y - (double)e3.y;  d = fma(f, f, d);
      f = (double)xv3.z - (double)e3.z;  d = fma(f, f, d);
      f = (double)xv3.w - (double)e3.w;  d = fma(f, f, d);
#pragma unroll
      for (int w = 1; w < 64; w <<= 1) d += __shfl_xor(d, w);
      int k = ch * CPT + kk;
      if (lt2d(d, k, b1, k1)) { b2 = b1; k2 = k1; b1 = d; k1 = k; }
      else if (lt2d(d, k, b2, k2)) { b2 = d; k2 = k; }
    }
    if (lane == 0) { pb1[task] = b1; pb2[task] = b2; pk1[task] = k1; pk2[task] = k2; }
  }
}

// ---------------- rescue stage 3: merge partials + np-quantization tie verdict ------
__global__ __launch_bounds__(256) void rescue_verdict(
    const float* __restrict__ x, const float* __restrict__ cb,
    const int* __restrict__ flaglist, const int* __restrict__ nflag,
    const double* __restrict__ pb1, const double* __restrict__ pb2,
    const int* __restrict__ pk1, const int* __restrict__ pk2,
    int* __restrict__ fidx) {
  int nf = *nflag; if (nf > MAXF) nf = MAXF;
  int fi = blockIdx.x;
  if (fi >= nf) return;
  int row = flaglist[fi];
  int c = row & (NC - 1);
  int t = threadIdx.x;
  __shared__ float xs[ND];
  __shared__ int sAB[2];
  __shared__ double sh_xe[2], sh_e2[2], sh_x2;
  for (int i = t; i < ND; i += 256) xs[i] = x[(long)row * ND + i];
  if (t == 0) {
    double m1 = 1e300, m2 = 1e300; int a1 = 0x7fffffff, a2 = 0x7fffffff;
    for (int p = 0; p < TPR; ++p) {
      long pi = (long)fi * TPR + p;
      merge_top2d(m1, a1, m2, a2, pb1[pi], pk1[pi], pb2[pi], pk2[pi]);
    }
    sAB[0] = a1; sAB[1] = a2;
  }
  __syncthreads();
  int A = sAB[0], B = sAB[1];
  int lane = t & 63, wvv = t >> 6;
  if (wvv < 2) {
    const float* e = cb + ((long)c * NK + (wvv ? B : A)) * ND;
    double xe = 0, e2 = 0;
    for (int j = lane; j < ND; j += 64) {
      double ev = (double)e[j], xv = (double)xs[j];
      xe = fma(xv, ev, xe);
      e2 = fma(ev, ev, e2);
    }
    for (int w = 1; w < 64; w <<= 1) { xe += __shfl_xor(xe, w); e2 += __shfl_xor(e2, w); }
    if (lane == 0) { sh_xe[wvv] = xe; sh_e2[wvv] = e2; }
  } else if (wvv == 2) {
    double x2 = 0;
    for (int j = lane; j < ND; j += 64) { double xv = (double)xs[j]; x2 = fma(xv, xv, x2); }
    for (int w = 1; w < 64; w <<= 1) x2 += __shfl_xor(x2, w);
    if (lane == 0) sh_x2 = x2;
  }
  __syncthreads();
  if (t == 0) {
    float x2f = (float)sh_x2;
    float e2A = (float)sh_e2[0], e2B = (float)sh_e2[1];
    double xeA = sh_xe[0], xeB = sh_xe[1];
    const double JX = 3.0e-6;
    int cntA = 0, cntB = 0;
    for (int u = -3; u <= 3; ++u) {
      float x2c = __uint_as_float((u32)((int)__float_as_uint(x2f) + u));
      for (int j = 0; j < 4; ++j) {
        double jit = (j == 2) ? JX : (j == 3) ? -JX : 0.0;
        float xeAf = (float)(xeA + jit);
        float xeBf = (float)(xeB - jit);
        float DA = __fadd_rn(__fsub_rn(x2c, __fmul_rn(2.0f, xeAf)), e2A);
        float DB = __fadd_rn(__fsub_rn(x2c, __fmul_rn(2.0f, xeBf)), e2B);
        bool pickA = (DA < DB) || (DA == DB && A < B);
        if (pickA) ++cntA; else ++cntB;
      }
    }
    int pick = (cntA > cntB) ? A : (cntB > cntA) ? B : (A < B ? A : B);
    fidx[row] = pick;
  }
}

// ---------------- gather x_q_st, loss, counts, embed_ind ----------------
__global__ __launch_bounds__(256) void gather_kernel(
    const float* __restrict__ x, const float* __restrict__ cb,
    const int* __restrict__ fidx, float* __restrict__ out,
    int* __restrict__ counts, double* __restrict__ loss) {
  int bid = blockIdx.x;                // b*NC + c
  int c = bid & (NC - 1);
  int t = threadIdx.x;
  int k = fidx[bid];
  const float* e  = cb + ((long)c * NK + k) * ND + t * 4;
  const float* xv = x + (long)bid * ND + t * 4;
  float* dst = out + (long)bid * ND + t * 4;
  float4 ev = *(const float4*)e;
  float4 x4 = *(const float4*)xv;
  float d0 = ev.x - x4.x, d1 = ev.y - x4.y, d2 = ev.z - x4.z, d3 = ev.w - x4.w;
  float4 o; o.x = x4.x + d0; o.y = x4.y + d1; o.z = x4.z + d2; o.w = x4.w + d3;
  *(float4*)dst = o;
  float ls = d0*d0 + d1*d1 + d2*d2 + d3*d3;
#pragma unroll
  for (int w = 1; w < 64; w <<= 1) ls += __shfl_xor(ls, w);
  __shared__ float part[4];
  if ((t & 63) == 0) part[t >> 6] = ls;
  __syncthreads();
  if (t == 0) {
    double tot = (double)part[0] + (double)part[1] + (double)part[2] + (double)part[3];
    atomicAdd(&loss[c], tot);
    out[XQ_OFF + 2 + bid] = (float)k;
    atomicAdd(&counts[c * NK + k], 1);
  }
}

__global__ __launch_bounds__(256) void finalize_kernel(const int* __restrict__ counts,
                                                       const double* __restrict__ loss,
                                                       float* __restrict__ out) {
  int t = threadIdx.x;
  int cnt = 0;
  for (int i = t; i < NC * NK; i += 256) cnt += (counts[i] == 0) ? 1 : 0;
#pragma unroll
  for (int w = 1; w < 64; w <<= 1) cnt += __shfl_xor(cnt, w);
  __shared__ int part[4];
  if ((t & 63) == 0) part[t >> 6] = cnt;
  __syncthreads();
  if (t == 0) {
    int total = part[0] + part[1] + part[2] + part[3];
    double s = loss[0] + loss[1] + loss[2] + loss[3];
    out[XQ_OFF + 0] = (float)(1.25 * s / (double)((long)NB * ND));
    out[XQ_OFF + 1] = (float)total;
  }
}

extern "C" void kernel_launch(void* const* d_in, const int* in_sizes, int n_in,
                              void* d_out, int out_size, void* d_ws, size_t ws_size,
                              hipStream_t stream) {
  (void)in_sizes; (void)n_in; (void)out_size;
  const float* x  = (const float*)d_in[0];
  const float* cb = (const float*)d_in[1];
  float* out = (float*)d_out;
  char* ws = (char*)d_ws;

  size_t sz_half = (size_t)NC * NK * ND * sizeof(f16);   // 64 MiB each
  f16* cbh = (f16*)(ws + 0 * sz_half);
  f16* cbl = (f16*)(ws + 1 * sz_half);
  f16* xh  = (f16*)(ws + 2 * sz_half);
  f16* xl  = (f16*)(ws + 3 * sz_half);
  size_t off = 4 * sz_half;
  float* e2np = (float*)(ws + off); off += (size_t)NC * NK * 4;
  u64*  wsA   = (u64*)(ws + off);   off += (size_t)NB * NC * 4 * 8;
  u64*  wsB   = (u64*)(ws + off);   off += (size_t)NB * NC * 4 * 8;
  int*  fidx  = (int*)(ws + off);   off += (size_t)NB * NC * 4;
  int*  counts= (int*)(ws + off);   off += (size_t)NC * NK * 4;
  double* loss= (double*)(ws + off);off += NC * 8;
  if (ws_size < off) {
    fprintf(stderr, "kernel_launch: workspace too small: need %zu, have %zu\n", off, ws_size);
    return;
  }
  // rescue scratch ALIASES cbh region (dead after vq_gemm2) — zero ws growth
  char* rs = ws;
  int*    nflag    = (int*)rs;
  int*    flaglist = (int*)(rs + 256);
  double* pb1      = (double*)(rs + 256 + MAXF * 4);
  double* pb2      = pb1 + (size_t)MAXF * TPR;
  int*    pk1      = (int*)(pb2 + (size_t)MAXF * TPR);
  int*    pk2      = pk1 + (size_t)MAXF * TPR;

  hipMemsetAsync(counts, 0, (size_t)NC * NK * 4, stream);
  hipMemsetAsync(loss, 0, NC * 8, stream);

  prep_split<<<NC * NT * KT, 256, 0, stream>>>(cb, cbh, cbl, 0);
  prep_split<<<NC * MT * KT, 256, 0, stream>>>(x, xh, xl, 1);
  row2_np<<<(NC * NK) / 32, 256, 0, stream>>>(cb, e2np);
  vq_gemm2<<<NC * 32 * 2, 512, 0, stream>>>(xh, xl, cbh, cbl, e2np, wsA, wsB);

  hipMemsetAsync(nflag, 0, sizeof(int), stream);
  flag_collect<<<(NB * NC) / 256, 256, 0, stream>>>(wsA, wsB, fidx, flaglist, nflag);
  rescue_scan<<<1024, 256, 0, stream>>>(x, cb, flaglist, nflag, pb1, pb2, pk1, pk2);
  rescue_verdict<<<MAXF, 256, 0, stream>>>(x, cb, flaglist, nflag, pb1, pb2, pk1, pk2, fidx);

  gather_kernel<<<NB * NC, 256, 0, stream>>>(x, cb, fidx, out, counts, loss);
  finalize_kernel<<<1, 256, 0, stream>>>(counts, loss, out);
}